// Round 8
// baseline (356.014 us; speedup 1.0000x reference)
//
#include <hip/hip_runtime.h>

// PDF sampler (NeRF proposal resampling), eval path.
// R=131072 rays, N=256 existing bins, num_samples=96 -> num_bins=97.
// out = [2, R, 97] fp32: [0]=euclidean (NEAR + bins*(FAR-NEAR)), [1]=spacing bins.
//
// Round-7 structure: ZERO LDS, zero DS ops, direct owner-writes.
//  - u is a uniform grid: m(c) = ceil(97c - 0.5) = first sample with u >= c.
//  - "below"=q covers samples j in [m(cdf[q]), m(cdf[q+1])). The owner lane of
//    q already holds cdf[q], cdf[q+1], bins[q], bins[q+1] (boundary values via
//    one-lane DPP shifts), so it computes and stores those samples DIRECTLY.
//  - With these inputs pdf<=1/sum(w)~0.0078 => 97*pdf<1 => every q covers <=1
//    sample: the 4 emits are single predicated stores. A guarded loop path
//    (execz-skipped) handles the general case for robustness.
//  - Cross-lane range stitching uses the SAME shuffled m value => gapless,
//    disjoint. Whole kernel: 2 float4 loads + 1 scalar load + ~140 VALU +
//    ~10 stores per wave. No __syncthreads anywhere.

#define NUM_RAYS 131072
#define NUM_EXISTING 256
#define NUM_BINS 97
#define EPS_W 1e-5f

constexpr int WAVES_PER_BLOCK = 4;
constexpr int BLOCK = 64 * WAVES_PER_BLOCK;
constexpr float U_STEP = 1.0f / (float)NUM_BINS;
constexpr float U_HALF = 0.5f / (float)NUM_BINS;

// v += dpp(v); bound_ctrl=true -> out-of-range source reads 0
template<int CTRL, int RMASK>
__device__ __forceinline__ float scan_add(float v) {
    int t = __builtin_amdgcn_update_dpp(0, __float_as_int(v), CTRL, RMASK, 0xF, true);
    return v + __int_as_float(t);
}
// lane l <- lane l-1 (wave_shr:1); lane 0 -> 0
__device__ __forceinline__ int shfl_up1_i(int v) {
    return __builtin_amdgcn_update_dpp(0, v, 0x138, 0xF, 0xF, true);
}
__device__ __forceinline__ float shfl_up1_f(float v) {
    return __int_as_float(shfl_up1_i(__float_as_int(v)));
}
// lane l <- lane l+1 (wave_shl:1); lane 63 -> 0 (patched by caller)
__device__ __forceinline__ float shfl_dn1_f(float v) {
    return __int_as_float(__builtin_amdgcn_update_dpp(0, __float_as_int(v), 0x130, 0xF, 0xF, true));
}

__device__ __forceinline__ void emit1(int lo, int hi, float cg0, float cg1,
                                      float bg0, float bg1,
                                      float* __restrict__ out_e,
                                      float* __restrict__ out_s)
{
    if (lo < hi) {   // covers exactly sample j=lo in the common case
        float denom = cg1 - cg0;
        denom = (denom < 1e-5f) ? 1.0f : denom;
        float u = fmaf((float)lo, U_STEP, U_HALF);
        float t = (u - cg0) * __builtin_amdgcn_rcpf(denom);
        t = fminf(fmaxf(t, 0.0f), 1.0f);
        float bins = fmaf(t, bg1 - bg0, bg0);
        out_e[lo] = fmaf(bins, 4.0f, 2.0f);   // NEAR + bins*(FAR-NEAR)
        out_s[lo] = bins;
    }
}

__device__ __forceinline__ void emit_loop(int lo, int hi, float cg0, float cg1,
                                          float bg0, float bg1,
                                          float* __restrict__ out_e,
                                          float* __restrict__ out_s)
{
    float denom = cg1 - cg0;
    denom = (denom < 1e-5f) ? 1.0f : denom;
    float rd = __builtin_amdgcn_rcpf(denom);
    float bd = bg1 - bg0;
    for (int j = lo; j < hi; ++j) {
        float u = fmaf((float)j, U_STEP, U_HALF);
        float t = fminf(fmaxf((u - cg0) * rd, 0.0f), 1.0f);
        float bins = fmaf(t, bd, bg0);
        out_e[j] = fmaf(bins, 4.0f, 2.0f);
        out_s[j] = bins;
    }
}

__global__ __launch_bounds__(BLOCK) void pdf_sample_kernel(
    const float* __restrict__ weights,
    const float* __restrict__ spacing_starts,
    const float* __restrict__ spacing_ends,
    float* __restrict__ out)
{
    const int wave = threadIdx.x >> 6;
    const int lane = threadIdx.x & 63;
    const int ray  = blockIdx.x * WAVES_PER_BLOCK + wave;

    const float4 w4 = reinterpret_cast<const float4*>(weights        + (size_t)ray * NUM_EXISTING)[lane];
    const float4 b4 = reinterpret_cast<const float4*>(spacing_starts + (size_t)ray * NUM_EXISTING)[lane];
    const float bend = spacing_ends[(size_t)ray * NUM_EXISTING + (NUM_EXISTING - 1)]; // wave-broadcast

    // ---- wave64 inclusive scan of per-lane sums, pure-VALU DPP ----
    float sl = (w4.x + w4.y) + (w4.z + w4.w);
    float v = sl;
    v = scan_add<0x111, 0xF>(v);   // row_shr:1
    v = scan_add<0x112, 0xF>(v);   // row_shr:2
    v = scan_add<0x114, 0xF>(v);   // row_shr:4
    v = scan_add<0x118, 0xF>(v);   // row_shr:8
    v = scan_add<0x142, 0xA>(v);   // row_bcast:15 -> rows 1,3
    v = scan_add<0x143, 0xC>(v);   // row_bcast:31 -> rows 2,3
    float total = __int_as_float(__builtin_amdgcn_readlane(__float_as_int(v), 63));
    float excl  = v - sl;

    // padding = relu(eps - w_sum); w += padding/N; w_sum += padding
    float padding = fmaxf(EPS_W - total, 0.0f);
    float inv     = __builtin_amdgcn_rcpf(total + padding);
    float padinv  = padding * inv * (1.0f / (float)NUM_EXISTING);

    // cdf[4l+1 .. 4l+4] = c0..c3 (lane-local)
    float cc = fmaf(excl, inv, (float)(4 * lane) * padinv);
    cc = fmaf(w4.x, inv, cc + padinv); float c0 = fminf(cc, 1.0f);
    cc = fmaf(w4.y, inv, cc + padinv); float c1 = fminf(cc, 1.0f);
    cc = fmaf(w4.z, inv, cc + padinv); float c2 = fminf(cc, 1.0f);
    cc = fmaf(w4.w, inv, cc + padinv); float c3 = fminf(cc, 1.0f);

    // m(c) = first sample index with u >= c ; c in [0,1] -> m in [0,97]
    int m0 = (int)ceilf(fmaf(97.0f, c0, -0.5f));
    int m1 = (int)ceilf(fmaf(97.0f, c1, -0.5f));
    int m2 = (int)ceilf(fmaf(97.0f, c2, -0.5f));
    int m3 = (int)ceilf(fmaf(97.0f, c3, -0.5f));

    int   s0   = shfl_up1_i(m3);   // m(cdf[4l])  ; lane0 -> 0 = m(cdf[0])
    float clo  = shfl_up1_f(c3);   // cdf[4l]     ; lane0 -> 0 = cdf[0]
    float bhi3 = shfl_dn1_f(b4.x); // bins[4l+4]  ; lane63 patched:
    if (lane == 63) bhi3 = bend;   //   bins[256] = spacing_ends last

    // forward monotone clamp: ranges [s0,e0),[e0,e1),[e1,e2),[e2,e3) are
    // disjoint & gapless; cross-lane stitched via the shuffled raw m3.
    int e0 = max(m0, s0);
    int e1 = max(m1, e0);
    int e2 = max(m2, e1);
    int e3 = max(m3, e2);

    float* out_e = out + (size_t)ray * NUM_BINS;
    float* out_s = out_e + (size_t)NUM_RAYS * NUM_BINS;

    // common case: each range holds 0 or 1 sample (97*pdf_max < 1)
    emit1(s0, e0, clo, c0, b4.x, b4.y, out_e, out_s);
    emit1(e0, e1, c0,  c1, b4.y, b4.z, out_e, out_s);
    emit1(e1, e2, c1,  c2, b4.z, b4.w, out_e, out_s);
    emit1(e2, e3, c2,  c3, b4.w, bhi3, out_e, out_s);

    // rare general case: any range with >=2 samples (execz-skipped otherwise).
    // diffs are >=0; OR > 1 iff some diff >= 2.
    if ((((e0 - s0) | (e1 - e0)) | ((e2 - e1) | (e3 - e2))) > 1) {
        emit_loop(s0 + 1, e0, clo, c0, b4.x, b4.y, out_e, out_s);
        emit_loop(e0 + 1, e1, c0,  c1, b4.y, b4.z, out_e, out_s);
        emit_loop(e1 + 1, e2, c1,  c2, b4.z, b4.w, out_e, out_s);
        emit_loop(e2 + 1, e3, c2,  c3, b4.w, bhi3, out_e, out_s);
    }
}

extern "C" void kernel_launch(void* const* d_in, const int* in_sizes, int n_in,
                              void* d_out, int out_size, void* d_ws, size_t ws_size,
                              hipStream_t stream) {
    const float* weights        = (const float*)d_in[0];
    const float* spacing_starts = (const float*)d_in[1];
    const float* spacing_ends   = (const float*)d_in[2];
    // d_in[3] = num_samples (int scalar) -- fixed at 96, baked in as NUM_BINS=97
    float* out = (float*)d_out;

    dim3 grid(NUM_RAYS / WAVES_PER_BLOCK);
    dim3 block(BLOCK);
    pdf_sample_kernel<<<grid, block, 0, stream>>>(weights, spacing_starts, spacing_ends, out);
}